// Round 7
// baseline (106.305 us; speedup 1.0000x reference)
//
#include <hip/hip_runtime.h>
#include <hip/hip_bf16.h>

typedef __bf16 bf16x8 __attribute__((ext_vector_type(8)));
typedef float f32x4 __attribute__((ext_vector_type(4)));
typedef float f32x16 __attribute__((ext_vector_type(16)));

__device__ __forceinline__ ushort f2bf(float f) {
  union { float f; unsigned u; } x; x.f = f;
  unsigned r = x.u + 0x7fffu + ((x.u >> 16) & 1u);
  return (ushort)(r >> 16);
}

__device__ __forceinline__ void gld_lds16(const void* g, void* l) {
  __builtin_amdgcn_global_load_lds(
      (const __attribute__((address_space(1))) void*)g,
      (__attribute__((address_space(3))) void*)l, 16, 0, 0);
}

// ---------------- fused f32 -> bf16 convert (all 5 tensors, 1 launch) ------
__global__ __launch_bounds__(256) void k_cvt_all(
    const float* __restrict__ q, const float* __restrict__ k,
    const float* __restrict__ v, const float* __restrict__ wi,
    const float* __restrict__ wo, ushort* __restrict__ dst) {
  const int NQ = 1048576;            // float4s per q/k/v
  const int NWI = 196608, NWO = 65536;
  const int total = 3 * NQ + NWI + NWO;
  int i = blockIdx.x * 256 + threadIdx.x;
  int stride = gridDim.x * 256;
  for (; i < total; i += stride) {
    const float* s; int j;
    if (i < NQ)              { s = q;  j = i; }
    else if (i < 2 * NQ)     { s = k;  j = i - NQ; }
    else if (i < 3 * NQ)     { s = v;  j = i - 2 * NQ; }
    else if (i < 3 * NQ + NWI) { s = wi; j = i - 3 * NQ; }
    else                     { s = wo; j = i - 3 * NQ - NWI; }
    float4 val = reinterpret_cast<const float4*>(s)[j];
    ushort4 o;
    o.x = f2bf(val.x); o.y = f2bf(val.y); o.z = f2bf(val.z); o.w = f2bf(val.w);
    reinterpret_cast<ushort4*>(dst)[i] = o;
  }
}

// ---------------- bf16 GEMM  C = A @ Bt^T + bias  (optional z0 scale) ------
#define GK 512
#define GN 512

__global__ __launch_bounds__(256) void k_gemm(
    const ushort* __restrict__ Abase, size_t az,
    const ushort* __restrict__ Btbase, size_t bz,
    const float* __restrict__ biasbase, int biz,
    void* __restrict__ Cbase, size_t cz,
    int out_bf16, float qs)
{
  int z = blockIdx.z;
  const ushort* A  = Abase  + az * z;
  const ushort* Bt = Btbase + bz * z;
  const float* bias = biasbase + (size_t)biz * z;
  float osc = (z == 0) ? qs : 1.0f;

  __shared__ ushort As[128 * 32];
  __shared__ ushort Bs[128 * 32];

  int tid = threadIdx.x;
  int wv = tid >> 6, ln = tid & 63;
  int l15 = ln & 15, lg = ln >> 4;
  int wm = wv >> 1, wn = wv & 1;
  int m0 = blockIdx.x * 128, n0 = blockIdx.y * 128;

  f32x4 acc[4][4] = {};

  for (int kt = 0; kt < GK / 32; ++kt) {
    __syncthreads();
#pragma unroll
    for (int h2 = 0; h2 < 2; ++h2) {
      int c = h2 * 256 + wv * 64 + ln;
      int row = c >> 2, kc = (c & 3) * 8;
      gld_lds16(A  + (size_t)(m0 + row) * GK + kt * 32 + kc,
                (char*)As + (h2 * 256 + wv * 64) * 16);
      gld_lds16(Bt + (size_t)(n0 + row) * GK + kt * 32 + kc,
                (char*)Bs + (h2 * 256 + wv * 64) * 16);
    }
    __syncthreads();
    bf16x8 af[4], bf[4];
#pragma unroll
    for (int mf = 0; mf < 4; ++mf)
      af[mf] = *reinterpret_cast<const bf16x8*>(&As[(wm * 64 + mf * 16 + l15) * 32 + lg * 8]);
#pragma unroll
    for (int nf = 0; nf < 4; ++nf)
      bf[nf] = *reinterpret_cast<const bf16x8*>(&Bs[(wn * 64 + nf * 16 + l15) * 32 + lg * 8]);
#pragma unroll
    for (int mf = 0; mf < 4; ++mf)
#pragma unroll
      for (int nf = 0; nf < 4; ++nf)
        acc[mf][nf] = __builtin_amdgcn_mfma_f32_16x16x32_bf16(af[mf], bf[nf], acc[mf][nf], 0, 0, 0);
  }

#pragma unroll
  for (int mf = 0; mf < 4; ++mf)
#pragma unroll
    for (int nf = 0; nf < 4; ++nf)
#pragma unroll
      for (int r = 0; r < 4; ++r) {
        int rr = m0 + wm * 64 + mf * 16 + lg * 4 + r;
        int cc = n0 + wn * 64 + nf * 16 + l15;
        float v = (acc[mf][nf][r] + bias[cc]) * osc;
        if (out_bf16)
          ((ushort*)Cbase + cz * z)[(size_t)rr * GN + cc] = f2bf(v);
        else
          ((float*)Cbase)[(size_t)rr * GN + cc] = v;
      }
}

// ---------------- sliding-window attention v6 (TLP: 960 x 4-wave, 32KB) ----
// block = (b,n,h,qquarter): 4 waves x 32 q-rows. Swapped-QK in-reg softmax
// (R4 structure). V staged transposed+swizzled in TWO 32KB halves (keys
// 0..255 then 256..511) -> 4 blocks/CU co-resident vs 2. ds_write_b64
// staging (4 keys/write). XCD-chunked blockIdx swizzle (960%8==0).
__global__ __launch_bounds__(256, 4) void k_attn(
    const ushort* __restrict__ qp, const ushort* __restrict__ kp,
    const ushort* __restrict__ vp, ushort* __restrict__ ctx)
{
  const int E = 512, SEQ = 4096;
  int bid0 = blockIdx.x;
  int bid = (bid0 & 7) * 120 + (bid0 >> 3);   // XCD-chunked (bijective)
  int qq = bid & 3;
  int h = (bid >> 2) & 7;
  int n = (bid >> 5) % 15;
  int b = bid / 480;
  int start = n * 256;

  int tid = threadIdx.x;
  int w = tid >> 6, ln = tid & 63;
  int l31 = ln & 31, hi = ln >> 5;

  size_t base = ((size_t)(b * SEQ + start)) * E + h * 64;
  const ushort* Kw = kp + base;
  const ushort* Vw = vp + base;
  const ushort* Qw = qp + base;

  __shared__ ushort Vt[16384];  // Vt[d=64][k=256 of half], 32KB, byte^=(d&7)<<4

  int q0 = qq * 128 + w * 32;

  // Q B-frags: lane l holds Q[q0 + (l&31)][d = i*16 + hi*8 + j]
  bf16x8 qf0, qf1, qf2, qf3;
  {
    const ushort* qr = Qw + (size_t)(q0 + l31) * E + hi * 8;
    qf0 = *reinterpret_cast<const bf16x8*>(qr + 0);
    qf1 = *reinterpret_cast<const bf16x8*>(qr + 16);
    qf2 = *reinterpret_cast<const bf16x8*>(qr + 32);
    qf3 = *reinterpret_cast<const bf16x8*>(qr + 48);
  }

  f32x16 c0 = {}, c1 = {};
  float psum = 0.f;
  const char* lb = (const char*)Vt;

  // staging geometry: thread t owns keys (t&63)*4..+4 (within half),
  // d-range (t>>6)*16..+16; packs 4 keys per ds_write_b64.
  int sk = (tid & 63) * 4;
  int sd = (tid >> 6) * 16;

#define STAGE_V(G)                                                            \
  {                                                                           \
    const ushort* src = Vw + (size_t)((G) * 256 + sk) * E + sd;               \
    union { uint4 q[2]; ushort u[16]; } R0, R1, R2, R3;                       \
    R0.q[0] = *(const uint4*)(src);         R0.q[1] = *(const uint4*)(src + 8);         \
    R1.q[0] = *(const uint4*)(src + E);     R1.q[1] = *(const uint4*)(src + E + 8);     \
    R2.q[0] = *(const uint4*)(src + 2 * E); R2.q[1] = *(const uint4*)(src + 2 * E + 8); \
    R3.q[0] = *(const uint4*)(src + 3 * E); R3.q[1] = *(const uint4*)(src + 3 * E + 8); \
    _Pragma("unroll")                                                         \
    for (int d0 = 0; d0 < 16; ++d0) {                                         \
      int d = sd + d0;                                                        \
      uint2 val;                                                              \
      val.x = (uint)R0.u[d0] | ((uint)R1.u[d0] << 16);                        \
      val.y = (uint)R2.u[d0] | ((uint)R3.u[d0] << 16);                        \
      int off = d * 512 + ((sk * 2) ^ ((d & 7) << 4));                        \
      *(uint2*)((char*)Vt + off) = val;                                       \
    }                                                                         \
  }

#define ATTN_BODY(KB, G)                                                      \
  {                                                                           \
    bf16x8 kf0, kf1, kf2, kf3;                                                \
    {                                                                         \
      const ushort* kr = Kw + (size_t)(((G) * 8 + (KB)) * 32 + l31) * E + hi * 8; \
      kf0 = *reinterpret_cast<const bf16x8*>(kr + 0);                         \
      kf1 = *reinterpret_cast<const bf16x8*>(kr + 16);                        \
      kf2 = *reinterpret_cast<const bf16x8*>(kr + 32);                        \
      kf3 = *reinterpret_cast<const bf16x8*>(kr + 48);                        \
    }                                                                         \
    bf16x8 vb00, vb01, vb10, vb11;                                            \
    {                                                                         \
      int row = l31, rowh = 32 + l31;                                         \
      int cb0 = (KB) * 64 + hi * 16;                                          \
      int cb1 = cb0 + 32;                                                     \
      int xr = (row & 7) << 4;                                                \
      vb00 = *reinterpret_cast<const bf16x8*>(lb + row * 512 + (cb0 ^ xr));   \
      vb01 = *reinterpret_cast<const bf16x8*>(lb + rowh * 512 + (cb0 ^ xr));  \
      vb10 = *reinterpret_cast<const bf16x8*>(lb + row * 512 + (cb1 ^ xr));   \
      vb11 = *reinterpret_cast<const bf16x8*>(lb + rowh * 512 + (cb1 ^ xr));  \
    }                                                                         \
    f32x16 s = {};                                                            \
    __builtin_amdgcn_s_setprio(1);                                            \
    s = __builtin_amdgcn_mfma_f32_32x32x16_bf16(kf0, qf0, s, 0, 0, 0);        \
    s = __builtin_amdgcn_mfma_f32_32x32x16_bf16(kf1, qf1, s, 0, 0, 0);        \
    s = __builtin_amdgcn_mfma_f32_32x32x16_bf16(kf2, qf2, s, 0, 0, 0);        \
    s = __builtin_amdgcn_mfma_f32_32x32x16_bf16(kf3, qf3, s, 0, 0, 0);        \
    __builtin_amdgcn_s_setprio(0);                                            \
    _Pragma("unroll")                                                         \
    for (int r = 0; r < 16; ++r)                                              \
      s[r] = __builtin_amdgcn_exp2f(s[r]);                                    \
    {                                                                         \
      float t0 = (s[0] + s[1]) + (s[2] + s[3]);                               \
      float t1 = (s[4] + s[5]) + (s[6] + s[7]);                               \
      float t2 = (s[8] + s[9]) + (s[10] + s[11]);                             \
      float t3 = (s[12] + s[13]) + (s[14] + s[15]);                           \
      psum += (t0 + t1) + (t2 + t3);                                          \
    }                                                                         \
    uint cw0, cw1, cw2, cw3, cw4, cw5, cw6, cw7;                              \
    asm("v_cvt_pk_bf16_f32 %0, %1, %2" : "=v"(cw0) : "v"(s[0]),  "v"(s[1]));  \
    asm("v_cvt_pk_bf16_f32 %0, %1, %2" : "=v"(cw1) : "v"(s[2]),  "v"(s[3]));  \
    asm("v_cvt_pk_bf16_f32 %0, %1, %2" : "=v"(cw2) : "v"(s[4]),  "v"(s[5]));  \
    asm("v_cvt_pk_bf16_f32 %0, %1, %2" : "=v"(cw3) : "v"(s[6]),  "v"(s[7]));  \
    asm("v_cvt_pk_bf16_f32 %0, %1, %2" : "=v"(cw4) : "v"(s[8]),  "v"(s[9]));  \
    asm("v_cvt_pk_bf16_f32 %0, %1, %2" : "=v"(cw5) : "v"(s[10]), "v"(s[11])); \
    asm("v_cvt_pk_bf16_f32 %0, %1, %2" : "=v"(cw6) : "v"(s[12]), "v"(s[13])); \
    asm("v_cvt_pk_bf16_f32 %0, %1, %2" : "=v"(cw7) : "v"(s[14]), "v"(s[15])); \
    asm("v_permlane32_swap_b32 %0, %1" : "+v"(cw0), "+v"(cw2));               \
    asm("v_permlane32_swap_b32 %0, %1" : "+v"(cw1), "+v"(cw3));               \
    asm("v_permlane32_swap_b32 %0, %1" : "+v"(cw4), "+v"(cw6));               \
    asm("v_permlane32_swap_b32 %0, %1" : "+v"(cw5), "+v"(cw7));               \
    union { uint u[4]; bf16x8 v; } A1, A2;                                    \
    A1.u[0] = cw0; A1.u[1] = cw1; A1.u[2] = cw2; A1.u[3] = cw3;               \
    A2.u[0] = cw4; A2.u[1] = cw5; A2.u[2] = cw6; A2.u[3] = cw7;               \
    __builtin_amdgcn_s_setprio(1);                                            \
    c0 = __builtin_amdgcn_mfma_f32_32x32x16_bf16(A1.v, vb00, c0, 0, 0, 0);    \
    c1 = __builtin_amdgcn_mfma_f32_32x32x16_bf16(A1.v, vb01, c1, 0, 0, 0);    \
    c0 = __builtin_amdgcn_mfma_f32_32x32x16_bf16(A2.v, vb10, c0, 0, 0, 0);    \
    c1 = __builtin_amdgcn_mfma_f32_32x32x16_bf16(A2.v, vb11, c1, 0, 0, 0);    \
    __builtin_amdgcn_s_setprio(0);                                            \
  }

  STAGE_V(0);
  __syncthreads();
#pragma unroll
  for (int kb = 0; kb < 8; ++kb) ATTN_BODY(kb, 0);
  __syncthreads();
  STAGE_V(1);
  __syncthreads();
#pragma unroll
  for (int kb = 0; kb < 8; ++kb) ATTN_BODY(kb, 1);

#undef STAGE_V
#undef ATTN_BODY

  // combine halves (lane l and l+32 hold same q = l&31), normalize, store
  psum += __shfl_xor(psum, 32);
  float rinv_me = 1.0f / psum;
  size_t orow0 = (size_t)b * 7680 + (size_t)n * 512 + q0;
#pragma unroll
  for (int r = 0; r < 16; ++r) {
    int qrel = (r & 3) + 8 * (r >> 2) + 4 * hi;
    float ri = __shfl(rinv_me, qrel);
    ushort* dst = ctx + (orow0 + qrel) * E + h * 64 + l31;
    dst[0]  = f2bf(c0[r] * ri);
    dst[32] = f2bf(c1[r] * ri);
  }
}

// ---------------- launch ----------------
extern "C" void kernel_launch(void* const* d_in, const int* in_sizes, int n_in,
                              void* d_out, int out_size, void* d_ws, size_t ws_size,
                              hipStream_t stream) {
  const float* query = (const float*)d_in[0];
  const float* key   = (const float*)d_in[1];
  const float* value = (const float*)d_in[2];
  const float* ipw   = (const float*)d_in[3];
  const float* ipb   = (const float*)d_in[4];
  const float* opw   = (const float*)d_in[5];
  const float* opb   = (const float*)d_in[6];

  ushort* qb  = (ushort*)d_ws;
  ushort* kb  = qb  + 4194304;
  ushort* vb  = kb  + 4194304;
  ushort* wib = vb  + 4194304;
  ushort* wob = wib + 786432;
  ushort* qp  = wob + 262144;
  ushort* kp  = qp  + 4194304;
  ushort* vp  = kp  + 4194304;
  ushort* ctx = vp  + 4194304;

  const float SC = 0.125f * 1.44269504088896340736f;  // fold scale*log2e into Q

  k_cvt_all<<<2048, 256, 0, stream>>>(query, key, value, ipw, opw, qb);

  k_gemm<<<dim3(64, 4, 3), 256, 0, stream>>>(
      qb, (size_t)4194304, wib, (size_t)262144, ipb, 512,
      (void*)qp, (size_t)4194304, 1, SC);

  k_attn<<<960, 256, 0, stream>>>(qp, kp, vp, ctx);

  k_gemm<<<dim3(120, 4, 1), 256, 0, stream>>>(
      ctx, (size_t)0, wob, (size_t)0, opb, 0,
      d_out, (size_t)0, 0, 1.0f);
}

// Round 8
// 87.752 us; speedup vs baseline: 1.2114x; 1.2114x over previous
//
#include <hip/hip_runtime.h>
#include <hip/hip_bf16.h>

typedef __bf16 bf16x8 __attribute__((ext_vector_type(8)));
typedef float f32x4 __attribute__((ext_vector_type(4)));
typedef float f32x16 __attribute__((ext_vector_type(16)));

__device__ __forceinline__ ushort f2bf(float f) {
  union { float f; unsigned u; } x; x.f = f;
  unsigned r = x.u + 0x7fffu + ((x.u >> 16) & 1u);
  return (ushort)(r >> 16);
}

__device__ __forceinline__ void gld_lds16(const void* g, void* l) {
  __builtin_amdgcn_global_load_lds(
      (const __attribute__((address_space(1))) void*)g,
      (__attribute__((address_space(3))) void*)l, 16, 0, 0);
}

// ---------------- fused f32 -> bf16 convert (all 5 tensors, 1 launch) ------
__global__ __launch_bounds__(256) void k_cvt_all(
    const float* __restrict__ q, const float* __restrict__ k,
    const float* __restrict__ v, const float* __restrict__ wi,
    const float* __restrict__ wo, ushort* __restrict__ dst) {
  const int NQ = 1048576;            // float4s per q/k/v
  const int NWI = 196608, NWO = 65536;
  const int total = 3 * NQ + NWI + NWO;
  int i = blockIdx.x * 256 + threadIdx.x;
  int stride = gridDim.x * 256;
  for (; i < total; i += stride) {
    const float* s; int j;
    if (i < NQ)              { s = q;  j = i; }
    else if (i < 2 * NQ)     { s = k;  j = i - NQ; }
    else if (i < 3 * NQ)     { s = v;  j = i - 2 * NQ; }
    else if (i < 3 * NQ + NWI) { s = wi; j = i - 3 * NQ; }
    else                     { s = wo; j = i - 3 * NQ - NWI; }
    float4 val = reinterpret_cast<const float4*>(s)[j];
    ushort4 o;
    o.x = f2bf(val.x); o.y = f2bf(val.y); o.z = f2bf(val.z); o.w = f2bf(val.w);
    reinterpret_cast<ushort4*>(dst)[i] = o;
  }
}

// ---------------- bf16 GEMM  C = A @ Bt^T + bias  (optional z0 scale) ------
#define GK 512
#define GN 512

__global__ __launch_bounds__(256) void k_gemm(
    const ushort* __restrict__ Abase, size_t az,
    const ushort* __restrict__ Btbase, size_t bz,
    const float* __restrict__ biasbase, int biz,
    void* __restrict__ Cbase, size_t cz,
    int out_bf16, float qs)
{
  int z = blockIdx.z;
  const ushort* A  = Abase  + az * z;
  const ushort* Bt = Btbase + bz * z;
  const float* bias = biasbase + (size_t)biz * z;
  float osc = (z == 0) ? qs : 1.0f;

  __shared__ ushort As[128 * 32];
  __shared__ ushort Bs[128 * 32];

  int tid = threadIdx.x;
  int wv = tid >> 6, ln = tid & 63;
  int l15 = ln & 15, lg = ln >> 4;
  int wm = wv >> 1, wn = wv & 1;
  int m0 = blockIdx.x * 128, n0 = blockIdx.y * 128;

  f32x4 acc[4][4] = {};

  for (int kt = 0; kt < GK / 32; ++kt) {
    __syncthreads();
#pragma unroll
    for (int h2 = 0; h2 < 2; ++h2) {
      int c = h2 * 256 + wv * 64 + ln;
      int row = c >> 2, kc = (c & 3) * 8;
      gld_lds16(A  + (size_t)(m0 + row) * GK + kt * 32 + kc,
                (char*)As + (h2 * 256 + wv * 64) * 16);
      gld_lds16(Bt + (size_t)(n0 + row) * GK + kt * 32 + kc,
                (char*)Bs + (h2 * 256 + wv * 64) * 16);
    }
    __syncthreads();
    bf16x8 af[4], bf[4];
#pragma unroll
    for (int mf = 0; mf < 4; ++mf)
      af[mf] = *reinterpret_cast<const bf16x8*>(&As[(wm * 64 + mf * 16 + l15) * 32 + lg * 8]);
#pragma unroll
    for (int nf = 0; nf < 4; ++nf)
      bf[nf] = *reinterpret_cast<const bf16x8*>(&Bs[(wn * 64 + nf * 16 + l15) * 32 + lg * 8]);
#pragma unroll
    for (int mf = 0; mf < 4; ++mf)
#pragma unroll
      for (int nf = 0; nf < 4; ++nf)
        acc[mf][nf] = __builtin_amdgcn_mfma_f32_16x16x32_bf16(af[mf], bf[nf], acc[mf][nf], 0, 0, 0);
  }

#pragma unroll
  for (int mf = 0; mf < 4; ++mf)
#pragma unroll
    for (int nf = 0; nf < 4; ++nf)
#pragma unroll
      for (int r = 0; r < 4; ++r) {
        int rr = m0 + wm * 64 + mf * 16 + lg * 4 + r;
        int cc = n0 + wn * 64 + nf * 16 + l15;
        float v = (acc[mf][nf][r] + bias[cc]) * osc;
        if (out_bf16)
          ((ushort*)Cbase + cz * z)[(size_t)rr * GN + cc] = f2bf(v);
        else
          ((float*)Cbase)[(size_t)rr * GN + cc] = v;
      }
}

// ---------------- sliding-window attention v7 (2 q-tiles/wave ILP) --------
// 480 blocks (b,n,h,qhalf) x 4 waves; each wave owns 64 q-rows as TWO
// independent 32-row tiles (A: q0.., B: q0+32..). The two tiles' QK/exp/
// pack/PV streams interleave (dual ILP) and SHARE K-frag loads + V ds_reads
// (halves per-q memory ops). Full V staged once in 64KB swizzled LDS.
__global__ __launch_bounds__(256, 2) void k_attn(
    const ushort* __restrict__ qp, const ushort* __restrict__ kp,
    const ushort* __restrict__ vp, ushort* __restrict__ ctx)
{
  const int E = 512, SEQ = 4096;
  int bid0 = blockIdx.x;
  int bid = (bid0 & 7) * 60 + (bid0 >> 3);   // XCD-chunked (480 % 8 == 0)
  int qh = bid & 1;
  int h = (bid >> 1) & 7;
  int n = (bid >> 4) % 15;
  int b = bid / 240;
  int start = n * 256;

  int tid = threadIdx.x;
  int w = tid >> 6, ln = tid & 63;
  int l31 = ln & 31, hi = ln >> 5;

  size_t base = ((size_t)(b * SEQ + start)) * E + h * 64;
  const ushort* Kw = kp + base;
  const ushort* Vw = vp + base;
  const ushort* Qw = qp + base;

  __shared__ ushort Vt[32768];  // Vt[d=64][k=512], 64KB, byte^=(d&7)<<4

  // ---- stage V transposed: thread t owns 8 keys x 16 d ----
  {
    int sk = (tid & 63) * 8;
    int sd = (tid >> 6) * 16;
    const ushort* src = Vw + (size_t)sk * E + sd;
    union { uint4 q[2]; ushort u[16]; } R0, R1, R2, R3, R4, R5, R6, R7;
    R0.q[0] = *(const uint4*)(src + 0 * E); R0.q[1] = *(const uint4*)(src + 0 * E + 8);
    R1.q[0] = *(const uint4*)(src + 1 * E); R1.q[1] = *(const uint4*)(src + 1 * E + 8);
    R2.q[0] = *(const uint4*)(src + 2 * E); R2.q[1] = *(const uint4*)(src + 2 * E + 8);
    R3.q[0] = *(const uint4*)(src + 3 * E); R3.q[1] = *(const uint4*)(src + 3 * E + 8);
    R4.q[0] = *(const uint4*)(src + 4 * E); R4.q[1] = *(const uint4*)(src + 4 * E + 8);
    R5.q[0] = *(const uint4*)(src + 5 * E); R5.q[1] = *(const uint4*)(src + 5 * E + 8);
    R6.q[0] = *(const uint4*)(src + 6 * E); R6.q[1] = *(const uint4*)(src + 6 * E + 8);
    R7.q[0] = *(const uint4*)(src + 7 * E); R7.q[1] = *(const uint4*)(src + 7 * E + 8);
#pragma unroll
    for (int d0 = 0; d0 < 16; ++d0) {
      int d = sd + d0;
      uint4 val;
      val.x = (uint)R0.u[d0] | ((uint)R1.u[d0] << 16);
      val.y = (uint)R2.u[d0] | ((uint)R3.u[d0] << 16);
      val.z = (uint)R4.u[d0] | ((uint)R5.u[d0] << 16);
      val.w = (uint)R6.u[d0] | ((uint)R7.u[d0] << 16);
      int off = d * 1024 + ((sk * 2) ^ ((d & 7) << 4));
      *(uint4*)((char*)Vt + off) = val;
    }
  }
  __syncthreads();

  int q0 = qh * 256 + w * 64;

  // Q B-frags for both tiles: lane l holds Q[qX + (l&31)][d = i*16 + hi*8 + j]
  bf16x8 qa0, qa1, qa2, qa3, qb0, qb1, qb2, qb3;
  {
    const ushort* qra = Qw + (size_t)(q0 + l31) * E + hi * 8;
    const ushort* qrb = qra + (size_t)32 * E;
    qa0 = *reinterpret_cast<const bf16x8*>(qra + 0);
    qa1 = *reinterpret_cast<const bf16x8*>(qra + 16);
    qa2 = *reinterpret_cast<const bf16x8*>(qra + 32);
    qa3 = *reinterpret_cast<const bf16x8*>(qra + 48);
    qb0 = *reinterpret_cast<const bf16x8*>(qrb + 0);
    qb1 = *reinterpret_cast<const bf16x8*>(qrb + 16);
    qb2 = *reinterpret_cast<const bf16x8*>(qrb + 32);
    qb3 = *reinterpret_cast<const bf16x8*>(qrb + 48);
  }

  f32x16 ca0 = {}, ca1 = {}, cb0_ = {}, cb1_ = {};
  float psa = 0.f, psb = 0.f;
  const char* lb = (const char*)Vt;

#pragma unroll
  for (int kb = 0; kb < 16; ++kb) {
    // shared K A-frags
    bf16x8 kf0, kf1, kf2, kf3;
    {
      const ushort* kr = Kw + (size_t)(kb * 32 + l31) * E + hi * 8;
      kf0 = *reinterpret_cast<const bf16x8*>(kr + 0);
      kf1 = *reinterpret_cast<const bf16x8*>(kr + 16);
      kf2 = *reinterpret_cast<const bf16x8*>(kr + 32);
      kf3 = *reinterpret_cast<const bf16x8*>(kr + 48);
    }
    // shared V B-frags
    bf16x8 vb00, vb01, vb10, vb11;
    {
      int row = l31, rowh = 32 + l31;
      int cb0 = kb * 64 + hi * 16;
      int cb1 = cb0 + 32;
      int xr0 = (row & 7) << 4;
      vb00 = *reinterpret_cast<const bf16x8*>(lb + row * 1024 + (cb0 ^ xr0));
      vb01 = *reinterpret_cast<const bf16x8*>(lb + rowh * 1024 + (cb0 ^ xr0));
      vb10 = *reinterpret_cast<const bf16x8*>(lb + row * 1024 + (cb1 ^ xr0));
      vb11 = *reinterpret_cast<const bf16x8*>(lb + rowh * 1024 + (cb1 ^ xr0));
    }

    // dual QK^T (independent chains, shared kf)
    f32x16 s1 = {}, s2 = {};
    __builtin_amdgcn_s_setprio(1);
    s1 = __builtin_amdgcn_mfma_f32_32x32x16_bf16(kf0, qa0, s1, 0, 0, 0);
    s2 = __builtin_amdgcn_mfma_f32_32x32x16_bf16(kf0, qb0, s2, 0, 0, 0);
    s1 = __builtin_amdgcn_mfma_f32_32x32x16_bf16(kf1, qa1, s1, 0, 0, 0);
    s2 = __builtin_amdgcn_mfma_f32_32x32x16_bf16(kf1, qb1, s2, 0, 0, 0);
    s1 = __builtin_amdgcn_mfma_f32_32x32x16_bf16(kf2, qa2, s1, 0, 0, 0);
    s2 = __builtin_amdgcn_mfma_f32_32x32x16_bf16(kf2, qb2, s2, 0, 0, 0);
    s1 = __builtin_amdgcn_mfma_f32_32x32x16_bf16(kf3, qa3, s1, 0, 0, 0);
    s2 = __builtin_amdgcn_mfma_f32_32x32x16_bf16(kf3, qb3, s2, 0, 0, 0);
    __builtin_amdgcn_s_setprio(0);

#pragma unroll
    for (int r = 0; r < 16; ++r) s1[r] = __builtin_amdgcn_exp2f(s1[r]);
#pragma unroll
    for (int r = 0; r < 16; ++r) s2[r] = __builtin_amdgcn_exp2f(s2[r]);
    {
      float t0 = (s1[0] + s1[1]) + (s1[2] + s1[3]);
      float t1 = (s1[4] + s1[5]) + (s1[6] + s1[7]);
      float t2 = (s1[8] + s1[9]) + (s1[10] + s1[11]);
      float t3 = (s1[12] + s1[13]) + (s1[14] + s1[15]);
      psa += (t0 + t1) + (t2 + t3);
      float u0 = (s2[0] + s2[1]) + (s2[2] + s2[3]);
      float u1 = (s2[4] + s2[5]) + (s2[6] + s2[7]);
      float u2 = (s2[8] + s2[9]) + (s2[10] + s2[11]);
      float u3 = (s2[12] + s2[13]) + (s2[14] + s2[15]);
      psb += (u0 + u1) + (u2 + u3);
    }

    // pack both tiles: swap(a,b): a=[a.lo,b.lo], b=[a.hi,b.hi]; pair i,i+2
    uint a0, a1, a2, a3, a4, a5, a6, a7;
    asm("v_cvt_pk_bf16_f32 %0, %1, %2" : "=v"(a0) : "v"(s1[0]),  "v"(s1[1]));
    asm("v_cvt_pk_bf16_f32 %0, %1, %2" : "=v"(a1) : "v"(s1[2]),  "v"(s1[3]));
    asm("v_cvt_pk_bf16_f32 %0, %1, %2" : "=v"(a2) : "v"(s1[4]),  "v"(s1[5]));
    asm("v_cvt_pk_bf16_f32 %0, %1, %2" : "=v"(a3) : "v"(s1[6]),  "v"(s1[7]));
    asm("v_cvt_pk_bf16_f32 %0, %1, %2" : "=v"(a4) : "v"(s1[8]),  "v"(s1[9]));
    asm("v_cvt_pk_bf16_f32 %0, %1, %2" : "=v"(a5) : "v"(s1[10]), "v"(s1[11]));
    asm("v_cvt_pk_bf16_f32 %0, %1, %2" : "=v"(a6) : "v"(s1[12]), "v"(s1[13]));
    asm("v_cvt_pk_bf16_f32 %0, %1, %2" : "=v"(a7) : "v"(s1[14]), "v"(s1[15]));
    asm("v_permlane32_swap_b32 %0, %1" : "+v"(a0), "+v"(a2));
    asm("v_permlane32_swap_b32 %0, %1" : "+v"(a1), "+v"(a3));
    asm("v_permlane32_swap_b32 %0, %1" : "+v"(a4), "+v"(a6));
    asm("v_permlane32_swap_b32 %0, %1" : "+v"(a5), "+v"(a7));
    uint b0, b1, b2, b3, b4, b5, b6, b7;
    asm("v_cvt_pk_bf16_f32 %0, %1, %2" : "=v"(b0) : "v"(s2[0]),  "v"(s2[1]));
    asm("v_cvt_pk_bf16_f32 %0, %1, %2" : "=v"(b1) : "v"(s2[2]),  "v"(s2[3]));
    asm("v_cvt_pk_bf16_f32 %0, %1, %2" : "=v"(b2) : "v"(s2[4]),  "v"(s2[5]));
    asm("v_cvt_pk_bf16_f32 %0, %1, %2" : "=v"(b3) : "v"(s2[6]),  "v"(s2[7]));
    asm("v_cvt_pk_bf16_f32 %0, %1, %2" : "=v"(b4) : "v"(s2[8]),  "v"(s2[9]));
    asm("v_cvt_pk_bf16_f32 %0, %1, %2" : "=v"(b5) : "v"(s2[10]), "v"(s2[11]));
    asm("v_cvt_pk_bf16_f32 %0, %1, %2" : "=v"(b6) : "v"(s2[12]), "v"(s2[13]));
    asm("v_cvt_pk_bf16_f32 %0, %1, %2" : "=v"(b7) : "v"(s2[14]), "v"(s2[15]));
    asm("v_permlane32_swap_b32 %0, %1" : "+v"(b0), "+v"(b2));
    asm("v_permlane32_swap_b32 %0, %1" : "+v"(b1), "+v"(b3));
    asm("v_permlane32_swap_b32 %0, %1" : "+v"(b4), "+v"(b6));
    asm("v_permlane32_swap_b32 %0, %1" : "+v"(b5), "+v"(b7));
    union { uint u[4]; bf16x8 v; } A1, A2, B1, B2;
    A1.u[0] = a0; A1.u[1] = a1; A1.u[2] = a2; A1.u[3] = a3;
    A2.u[0] = a4; A2.u[1] = a5; A2.u[2] = a6; A2.u[3] = a7;
    B1.u[0] = b0; B1.u[1] = b1; B1.u[2] = b2; B1.u[3] = b3;
    B2.u[0] = b4; B2.u[1] = b5; B2.u[2] = b6; B2.u[3] = b7;

    // dual PV, shared vb frags
    __builtin_amdgcn_s_setprio(1);
    ca0  = __builtin_amdgcn_mfma_f32_32x32x16_bf16(A1.v, vb00, ca0, 0, 0, 0);
    cb0_ = __builtin_amdgcn_mfma_f32_32x32x16_bf16(B1.v, vb00, cb0_, 0, 0, 0);
    ca1  = __builtin_amdgcn_mfma_f32_32x32x16_bf16(A1.v, vb01, ca1, 0, 0, 0);
    cb1_ = __builtin_amdgcn_mfma_f32_32x32x16_bf16(B1.v, vb01, cb1_, 0, 0, 0);
    ca0  = __builtin_amdgcn_mfma_f32_32x32x16_bf16(A2.v, vb10, ca0, 0, 0, 0);
    cb0_ = __builtin_amdgcn_mfma_f32_32x32x16_bf16(B2.v, vb10, cb0_, 0, 0, 0);
    ca1  = __builtin_amdgcn_mfma_f32_32x32x16_bf16(A2.v, vb11, ca1, 0, 0, 0);
    cb1_ = __builtin_amdgcn_mfma_f32_32x32x16_bf16(B2.v, vb11, cb1_, 0, 0, 0);
    __builtin_amdgcn_s_setprio(0);
  }

  // normalize + store both tiles
  psa += __shfl_xor(psa, 32);
  psb += __shfl_xor(psb, 32);
  float ria = 1.0f / psa;
  float rib = 1.0f / psb;
  size_t orow0 = (size_t)b * 7680 + (size_t)n * 512 + q0;
#pragma unroll
  for (int r = 0; r < 16; ++r) {
    int qrel = (r & 3) + 8 * (r >> 2) + 4 * hi;
    float r1 = __shfl(ria, qrel);
    float r2 = __shfl(rib, qrel);
    ushort* dA = ctx + (orow0 + qrel) * E + h * 64 + l31;
    ushort* dB = ctx + (orow0 + 32 + qrel) * E + h * 64 + l31;
    dA[0]  = f2bf(ca0[r] * r1);
    dA[32] = f2bf(ca1[r] * r1);
    dB[0]  = f2bf(cb0_[r] * r2);
    dB[32] = f2bf(cb1_[r] * r2);
  }
}

// ---------------- launch ----------------
extern "C" void kernel_launch(void* const* d_in, const int* in_sizes, int n_in,
                              void* d_out, int out_size, void* d_ws, size_t ws_size,
                              hipStream_t stream) {
  const float* query = (const float*)d_in[0];
  const float* key   = (const float*)d_in[1];
  const float* value = (const float*)d_in[2];
  const float* ipw   = (const float*)d_in[3];
  const float* ipb   = (const float*)d_in[4];
  const float* opw   = (const float*)d_in[5];
  const float* opb   = (const float*)d_in[6];

  ushort* qb  = (ushort*)d_ws;
  ushort* kb  = qb  + 4194304;
  ushort* vb  = kb  + 4194304;
  ushort* wib = vb  + 4194304;
  ushort* wob = wib + 786432;
  ushort* qp  = wob + 262144;
  ushort* kp  = qp  + 4194304;
  ushort* vp  = kp  + 4194304;
  ushort* ctx = vp  + 4194304;

  const float SC = 0.125f * 1.44269504088896340736f;  // fold scale*log2e into Q

  k_cvt_all<<<2048, 256, 0, stream>>>(query, key, value, ipw, opw, qb);

  k_gemm<<<dim3(64, 4, 3), 256, 0, stream>>>(
      qb, (size_t)4194304, wib, (size_t)262144, ipb, 512,
      (void*)qp, (size_t)4194304, 1, SC);

  k_attn<<<480, 256, 0, stream>>>(qp, kp, vp, ctx);

  k_gemm<<<dim3(120, 4, 1), 256, 0, stream>>>(
      ctx, (size_t)0, wob, (size_t)0, opb, 0,
      d_out, (size_t)0, 0, 1.0f);
}

// Round 9
// 86.883 us; speedup vs baseline: 1.2235x; 1.0100x over previous
//
#include <hip/hip_runtime.h>
#include <hip/hip_bf16.h>

typedef __bf16 bf16x8 __attribute__((ext_vector_type(8)));
typedef float f32x4 __attribute__((ext_vector_type(4)));
typedef float f32x16 __attribute__((ext_vector_type(16)));

__device__ __forceinline__ ushort f2bf(float f) {
  union { float f; unsigned u; } x; x.f = f;
  unsigned r = x.u + 0x7fffu + ((x.u >> 16) & 1u);
  return (ushort)(r >> 16);
}

__device__ __forceinline__ void gld_lds16(const void* g, void* l) {
  __builtin_amdgcn_global_load_lds(
      (const __attribute__((address_space(1))) void*)g,
      (__attribute__((address_space(3))) void*)l, 16, 0, 0);
}

// ---------------- f32 -> bf16 convert (weights only now) ----------------
__global__ __launch_bounds__(256) void k_cvt_w(
    const float* __restrict__ wi, const float* __restrict__ wo,
    ushort* __restrict__ dst) {
  const int NWI = 196608, NWO = 65536;   // float4 counts
  const int total = NWI + NWO;
  int i = blockIdx.x * 256 + threadIdx.x;
  int stride = gridDim.x * 256;
  for (; i < total; i += stride) {
    const float* s; int j;
    if (i < NWI) { s = wi; j = i; }
    else         { s = wo; j = i - NWI; }
    float4 val = reinterpret_cast<const float4*>(s)[j];
    ushort4 o;
    o.x = f2bf(val.x); o.y = f2bf(val.y); o.z = f2bf(val.z); o.w = f2bf(val.w);
    reinterpret_cast<ushort4*>(dst)[i] = o;
  }
}

// ---------------- bf16 GEMM  C = A @ Bt^T + bias ----------------
// A: either bf16 (Ab) or f32 (za0/za1/za2 selected by z, converted in
// staging via cvt_pk). Bt: 512x512 bf16 row-major (N x K). 128x128 tile,
// BK=32, 256 threads (4 waves, 2x2).
#define GK 512
#define GN 512

__global__ __launch_bounds__(256) void k_gemm(
    const ushort* __restrict__ Ab,          // bf16 A (if !a_f32)
    const float* __restrict__ za0,          // f32 A per z (if a_f32)
    const float* __restrict__ za1,
    const float* __restrict__ za2,
    const ushort* __restrict__ Btbase, size_t bz,
    const float* __restrict__ biasbase, int biz,
    void* __restrict__ Cbase, size_t cz,
    int out_bf16, float qs, int a_f32)
{
  int z = blockIdx.z;
  const float* A32 = (z == 0) ? za0 : (z == 1) ? za1 : za2;
  const ushort* Bt = Btbase + bz * z;
  const float* bias = biasbase + (size_t)biz * z;
  float osc = (z == 0) ? qs : 1.0f;

  __shared__ ushort As[128 * 32];
  __shared__ ushort Bs[128 * 32];

  int tid = threadIdx.x;
  int wv = tid >> 6, ln = tid & 63;
  int l15 = ln & 15, lg = ln >> 4;
  int wm = wv >> 1, wn = wv & 1;
  int m0 = blockIdx.x * 128, n0 = blockIdx.y * 128;

  f32x4 acc[4][4] = {};

  for (int kt = 0; kt < GK / 32; ++kt) {
    __syncthreads();
    // B staging: global_load_lds (bf16 weights)
#pragma unroll
    for (int h2 = 0; h2 < 2; ++h2) {
      int c = h2 * 256 + wv * 64 + ln;
      int row = c >> 2, kc = (c & 3) * 8;
      gld_lds16(Bt + (size_t)(n0 + row) * GK + kt * 32 + kc,
                (char*)Bs + (h2 * 256 + wv * 64) * 16);
    }
    // A staging
    if (a_f32) {
      // thread t: row = t>>1, k-half = (t&1)*16; 16 f32 -> 16 bf16
      int row = tid >> 1, kh = (tid & 1) * 16;
      const float* af = A32 + (size_t)(m0 + row) * GK + kt * 32 + kh;
      float4 f0 = reinterpret_cast<const float4*>(af)[0];
      float4 f1 = reinterpret_cast<const float4*>(af)[1];
      float4 f2 = reinterpret_cast<const float4*>(af)[2];
      float4 f3 = reinterpret_cast<const float4*>(af)[3];
      uint w0, w1, w2, w3, w4, w5, w6, w7;
      asm("v_cvt_pk_bf16_f32 %0, %1, %2" : "=v"(w0) : "v"(f0.x), "v"(f0.y));
      asm("v_cvt_pk_bf16_f32 %0, %1, %2" : "=v"(w1) : "v"(f0.z), "v"(f0.w));
      asm("v_cvt_pk_bf16_f32 %0, %1, %2" : "=v"(w2) : "v"(f1.x), "v"(f1.y));
      asm("v_cvt_pk_bf16_f32 %0, %1, %2" : "=v"(w3) : "v"(f1.z), "v"(f1.w));
      asm("v_cvt_pk_bf16_f32 %0, %1, %2" : "=v"(w4) : "v"(f2.x), "v"(f2.y));
      asm("v_cvt_pk_bf16_f32 %0, %1, %2" : "=v"(w5) : "v"(f2.z), "v"(f2.w));
      asm("v_cvt_pk_bf16_f32 %0, %1, %2" : "=v"(w6) : "v"(f3.x), "v"(f3.y));
      asm("v_cvt_pk_bf16_f32 %0, %1, %2" : "=v"(w7) : "v"(f3.z), "v"(f3.w));
      char* dst = (char*)As + ((size_t)row * 32 + kh) * 2;
      uint4 p0; p0.x = w0; p0.y = w1; p0.z = w2; p0.w = w3;
      uint4 p1; p1.x = w4; p1.y = w5; p1.z = w6; p1.w = w7;
      reinterpret_cast<uint4*>(dst)[0] = p0;
      reinterpret_cast<uint4*>(dst)[1] = p1;
    } else {
#pragma unroll
      for (int h2 = 0; h2 < 2; ++h2) {
        int c = h2 * 256 + wv * 64 + ln;
        int row = c >> 2, kc = (c & 3) * 8;
        gld_lds16(Ab + (size_t)(m0 + row) * GK + kt * 32 + kc,
                  (char*)As + (h2 * 256 + wv * 64) * 16);
      }
    }
    __syncthreads();
    bf16x8 af[4], bf[4];
#pragma unroll
    for (int mf = 0; mf < 4; ++mf)
      af[mf] = *reinterpret_cast<const bf16x8*>(&As[(wm * 64 + mf * 16 + l15) * 32 + lg * 8]);
#pragma unroll
    for (int nf = 0; nf < 4; ++nf)
      bf[nf] = *reinterpret_cast<const bf16x8*>(&Bs[(wn * 64 + nf * 16 + l15) * 32 + lg * 8]);
#pragma unroll
    for (int mf = 0; mf < 4; ++mf)
#pragma unroll
      for (int nf = 0; nf < 4; ++nf)
        acc[mf][nf] = __builtin_amdgcn_mfma_f32_16x16x32_bf16(af[mf], bf[nf], acc[mf][nf], 0, 0, 0);
  }

#pragma unroll
  for (int mf = 0; mf < 4; ++mf)
#pragma unroll
    for (int nf = 0; nf < 4; ++nf)
#pragma unroll
      for (int r = 0; r < 4; ++r) {
        int rr = m0 + wm * 64 + mf * 16 + lg * 4 + r;
        int cc = n0 + wn * 64 + nf * 16 + l15;
        float v = (acc[mf][nf][r] + bias[cc]) * osc;
        if (out_bf16)
          ((ushort*)Cbase + cz * z)[(size_t)rr * GN + cc] = f2bf(v);
        else
          ((float*)Cbase)[(size_t)rr * GN + cc] = v;
      }
}

// ---------------- sliding-window attention v7 (2 q-tiles/wave ILP) --------
// (unchanged from R8 — 480 blocks x 4 waves, 64 q-rows/wave as two
// independent 32-row tiles sharing K-frags + V ds_reads)
__global__ __launch_bounds__(256, 2) void k_attn(
    const ushort* __restrict__ qp, const ushort* __restrict__ kp,
    const ushort* __restrict__ vp, ushort* __restrict__ ctx)
{
  const int E = 512, SEQ = 4096;
  int bid0 = blockIdx.x;
  int bid = (bid0 & 7) * 60 + (bid0 >> 3);   // XCD-chunked (480 % 8 == 0)
  int qh = bid & 1;
  int h = (bid >> 1) & 7;
  int n = (bid >> 4) % 15;
  int b = bid / 240;
  int start = n * 256;

  int tid = threadIdx.x;
  int w = tid >> 6, ln = tid & 63;
  int l31 = ln & 31, hi = ln >> 5;

  size_t base = ((size_t)(b * SEQ + start)) * E + h * 64;
  const ushort* Kw = kp + base;
  const ushort* Vw = vp + base;
  const ushort* Qw = qp + base;

  __shared__ ushort Vt[32768];  // Vt[d=64][k=512], 64KB, byte^=(d&7)<<4

  // ---- stage V transposed: thread t owns 8 keys x 16 d ----
  {
    int sk = (tid & 63) * 8;
    int sd = (tid >> 6) * 16;
    const ushort* src = Vw + (size_t)sk * E + sd;
    union { uint4 q[2]; ushort u[16]; } R0, R1, R2, R3, R4, R5, R6, R7;
    R0.q[0] = *(const uint4*)(src + 0 * E); R0.q[1] = *(const uint4*)(src + 0 * E + 8);
    R1.q[0] = *(const uint4*)(src + 1 * E); R1.q[1] = *(const uint4*)(src + 1 * E + 8);
    R2.q[0] = *(const uint4*)(src + 2 * E); R2.q[1] = *(const uint4*)(src + 2 * E + 8);
    R3.q[0] = *(const uint4*)(src + 3 * E); R3.q[1] = *(const uint4*)(src + 3 * E + 8);
    R4.q[0] = *(const uint4*)(src + 4 * E); R4.q[1] = *(const uint4*)(src + 4 * E + 8);
    R5.q[0] = *(const uint4*)(src + 5 * E); R5.q[1] = *(const uint4*)(src + 5 * E + 8);
    R6.q[0] = *(const uint4*)(src + 6 * E); R6.q[1] = *(const uint4*)(src + 6 * E + 8);
    R7.q[0] = *(const uint4*)(src + 7 * E); R7.q[1] = *(const uint4*)(src + 7 * E + 8);
#pragma unroll
    for (int d0 = 0; d0 < 16; ++d0) {
      int d = sd + d0;
      uint4 val;
      val.x = (uint)R0.u[d0] | ((uint)R1.u[d0] << 16);
      val.y = (uint)R2.u[d0] | ((uint)R3.u[d0] << 16);
      val.z = (uint)R4.u[d0] | ((uint)R5.u[d0] << 16);
      val.w = (uint)R6.u[d0] | ((uint)R7.u[d0] << 16);
      int off = d * 1024 + ((sk * 2) ^ ((d & 7) << 4));
      *(uint4*)((char*)Vt + off) = val;
    }
  }
  __syncthreads();

  int q0 = qh * 256 + w * 64;

  bf16x8 qa0, qa1, qa2, qa3, qb0, qb1, qb2, qb3;
  {
    const ushort* qra = Qw + (size_t)(q0 + l31) * E + hi * 8;
    const ushort* qrb = qra + (size_t)32 * E;
    qa0 = *reinterpret_cast<const bf16x8*>(qra + 0);
    qa1 = *reinterpret_cast<const bf16x8*>(qra + 16);
    qa2 = *reinterpret_cast<const bf16x8*>(qra + 32);
    qa3 = *reinterpret_cast<const bf16x8*>(qra + 48);
    qb0 = *reinterpret_cast<const bf16x8*>(qrb + 0);
    qb1 = *reinterpret_cast<const bf16x8*>(qrb + 16);
    qb2 = *reinterpret_cast<const bf16x8*>(qrb + 32);
    qb3 = *reinterpret_cast<const bf16x8*>(qrb + 48);
  }

  f32x16 ca0 = {}, ca1 = {}, cb0_ = {}, cb1_ = {};
  float psa = 0.f, psb = 0.f;
  const char* lb = (const char*)Vt;

#pragma unroll
  for (int kb = 0; kb < 16; ++kb) {
    bf16x8 kf0, kf1, kf2, kf3;
    {
      const ushort* kr = Kw + (size_t)(kb * 32 + l31) * E + hi * 8;
      kf0 = *reinterpret_cast<const bf16x8*>(kr + 0);
      kf1 = *reinterpret_cast<const bf16x8*>(kr + 16);
      kf2 = *reinterpret_cast<const bf16x8*>(kr + 32);
      kf3 = *reinterpret_cast<const bf16x8*>(kr + 48);
    }
    bf16x8 vb00, vb01, vb10, vb11;
    {
      int row = l31, rowh = 32 + l31;
      int cb0 = kb * 64 + hi * 16;
      int cb1 = cb0 + 32;
      int xr0 = (row & 7) << 4;
      vb00 = *reinterpret_cast<const bf16x8*>(lb + row * 1024 + (cb0 ^ xr0));
      vb01 = *reinterpret_cast<const bf16x8*>(lb + rowh * 1024 + (cb0 ^ xr0));
      vb10 = *reinterpret_cast<const bf16x8*>(lb + row * 1024 + (cb1 ^ xr0));
      vb11 = *reinterpret_cast<const bf16x8*>(lb + rowh * 1024 + (cb1 ^ xr0));
    }

    f32x16 s1 = {}, s2 = {};
    __builtin_amdgcn_s_setprio(1);
    s1 = __builtin_amdgcn_mfma_f32_32x32x16_bf16(kf0, qa0, s1, 0, 0, 0);
    s2 = __builtin_amdgcn_mfma_f32_32x32x16_bf16(kf0, qb0, s2, 0, 0, 0);
    s1 = __builtin_amdgcn_mfma_f32_32x32x16_bf16(kf1, qa1, s1, 0, 0, 0);
    s2 = __builtin_amdgcn_mfma_f32_32x32x16_bf16(kf1, qb1, s2, 0, 0, 0);
    s1 = __builtin_amdgcn_mfma_f32_32x32x16_bf16(kf2, qa2, s1, 0, 0, 0);
    s2 = __builtin_amdgcn_mfma_f32_32x32x16_bf16(kf2, qb2, s2, 0, 0, 0);
    s1 = __builtin_amdgcn_mfma_f32_32x32x16_bf16(kf3, qa3, s1, 0, 0, 0);
    s2 = __builtin_amdgcn_mfma_f32_32x32x16_bf16(kf3, qb3, s2, 0, 0, 0);
    __builtin_amdgcn_s_setprio(0);

#pragma unroll
    for (int r = 0; r < 16; ++r) s1[r] = __builtin_amdgcn_exp2f(s1[r]);
#pragma unroll
    for (int r = 0; r < 16; ++r) s2[r] = __builtin_amdgcn_exp2f(s2[r]);
    {
      float t0 = (s1[0] + s1[1]) + (s1[2] + s1[3]);
      float t1 = (s1[4] + s1[5]) + (s1[6] + s1[7]);
      float t2 = (s1[8] + s1[9]) + (s1[10] + s1[11]);
      float t3 = (s1[12] + s1[13]) + (s1[14] + s1[15]);
      psa += (t0 + t1) + (t2 + t3);
      float u0 = (s2[0] + s2[1]) + (s2[2] + s2[3]);
      float u1 = (s2[4] + s2[5]) + (s2[6] + s2[7]);
      float u2 = (s2[8] + s2[9]) + (s2[10] + s2[11]);
      float u3 = (s2[12] + s2[13]) + (s2[14] + s2[15]);
      psb += (u0 + u1) + (u2 + u3);
    }

    uint a0, a1, a2, a3, a4, a5, a6, a7;
    asm("v_cvt_pk_bf16_f32 %0, %1, %2" : "=v"(a0) : "v"(s1[0]),  "v"(s1[1]));
    asm("v_cvt_pk_bf16_f32 %0, %1, %2" : "=v"(a1) : "v"(s1[2]),  "v"(s1[3]));
    asm("v_cvt_pk_bf16_f32 %0, %1, %2" : "=v"(a2) : "v"(s1[4]),  "v"(s1[5]));
    asm("v_cvt_pk_bf16_f32 %0, %1, %2" : "=v"(a3) : "v"(s1[6]),  "v"(s1[7]));
    asm("v_cvt_pk_bf16_f32 %0, %1, %2" : "=v"(a4) : "v"(s1[8]),  "v"(s1[9]));
    asm("v_cvt_pk_bf16_f32 %0, %1, %2" : "=v"(a5) : "v"(s1[10]), "v"(s1[11]));
    asm("v_cvt_pk_bf16_f32 %0, %1, %2" : "=v"(a6) : "v"(s1[12]), "v"(s1[13]));
    asm("v_cvt_pk_bf16_f32 %0, %1, %2" : "=v"(a7) : "v"(s1[14]), "v"(s1[15]));
    asm("v_permlane32_swap_b32 %0, %1" : "+v"(a0), "+v"(a2));
    asm("v_permlane32_swap_b32 %0, %1" : "+v"(a1), "+v"(a3));
    asm("v_permlane32_swap_b32 %0, %1" : "+v"(a4), "+v"(a6));
    asm("v_permlane32_swap_b32 %0, %1" : "+v"(a5), "+v"(a7));
    uint b0, b1, b2, b3, b4, b5, b6, b7;
    asm("v_cvt_pk_bf16_f32 %0, %1, %2" : "=v"(b0) : "v"(s2[0]),  "v"(s2[1]));
    asm("v_cvt_pk_bf16_f32 %0, %1, %2" : "=v"(b1) : "v"(s2[2]),  "v"(s2[3]));
    asm("v_cvt_pk_bf16_f32 %0, %1, %2" : "=v"(b2) : "v"(s2[4]),  "v"(s2[5]));
    asm("v_cvt_pk_bf16_f32 %0, %1, %2" : "=v"(b3) : "v"(s2[6]),  "v"(s2[7]));
    asm("v_cvt_pk_bf16_f32 %0, %1, %2" : "=v"(b4) : "v"(s2[8]),  "v"(s2[9]));
    asm("v_cvt_pk_bf16_f32 %0, %1, %2" : "=v"(b5) : "v"(s2[10]), "v"(s2[11]));
    asm("v_cvt_pk_bf16_f32 %0, %1, %2" : "=v"(b6) : "v"(s2[12]), "v"(s2[13]));
    asm("v_cvt_pk_bf16_f32 %0, %1, %2" : "=v"(b7) : "v"(s2[14]), "v"(s2[15]));
    asm("v_permlane32_swap_b32 %0, %1" : "+v"(b0), "+v"(b2));
    asm("v_permlane32_swap_b32 %0, %1" : "+v"(b1), "+v"(b3));
    asm("v_permlane32_swap_b32 %0, %1" : "+v"(b4), "+v"(b6));
    asm("v_permlane32_swap_b32 %0, %1" : "+v"(b5), "+v"(b7));
    union { uint u[4]; bf16x8 v; } A1, A2, B1, B2;
    A1.u[0] = a0; A1.u[1] = a1; A1.u[2] = a2; A1.u[3] = a3;
    A2.u[0] = a4; A2.u[1] = a5; A2.u[2] = a6; A2.u[3] = a7;
    B1.u[0] = b0; B1.u[1] = b1; B1.u[2] = b2; B1.u[3] = b3;
    B2.u[0] = b4; B2.u[1] = b5; B2.u[2] = b6; B2.u[3] = b7;

    __builtin_amdgcn_s_setprio(1);
    ca0  = __builtin_amdgcn_mfma_f32_32x32x16_bf16(A1.v, vb00, ca0, 0, 0, 0);
    cb0_ = __builtin_amdgcn_mfma_f32_32x32x16_bf16(B1.v, vb00, cb0_, 0, 0, 0);
    ca1  = __builtin_amdgcn_mfma_f32_32x32x16_bf16(A1.v, vb01, ca1, 0, 0, 0);
    cb1_ = __builtin_amdgcn_mfma_f32_32x32x16_bf16(B1.v, vb01, cb1_, 0, 0, 0);
    ca0  = __builtin_amdgcn_mfma_f32_32x32x16_bf16(A2.v, vb10, ca0, 0, 0, 0);
    cb0_ = __builtin_amdgcn_mfma_f32_32x32x16_bf16(B2.v, vb10, cb0_, 0, 0, 0);
    ca1  = __builtin_amdgcn_mfma_f32_32x32x16_bf16(A2.v, vb11, ca1, 0, 0, 0);
    cb1_ = __builtin_amdgcn_mfma_f32_32x32x16_bf16(B2.v, vb11, cb1_, 0, 0, 0);
    __builtin_amdgcn_s_setprio(0);
  }

  psa += __shfl_xor(psa, 32);
  psb += __shfl_xor(psb, 32);
  float ria = 1.0f / psa;
  float rib = 1.0f / psb;
  size_t orow0 = (size_t)b * 7680 + (size_t)n * 512 + q0;
#pragma unroll
  for (int r = 0; r < 16; ++r) {
    int qrel = (r & 3) + 8 * (r >> 2) + 4 * hi;
    float r1 = __shfl(ria, qrel);
    float r2 = __shfl(rib, qrel);
    ushort* dA = ctx + (orow0 + qrel) * E + h * 64 + l31;
    ushort* dB = ctx + (orow0 + 32 + qrel) * E + h * 64 + l31;
    dA[0]  = f2bf(ca0[r] * r1);
    dA[32] = f2bf(ca1[r] * r1);
    dB[0]  = f2bf(cb0_[r] * r2);
    dB[32] = f2bf(cb1_[r] * r2);
  }
}

// ---------------- launch ----------------
extern "C" void kernel_launch(void* const* d_in, const int* in_sizes, int n_in,
                              void* d_out, int out_size, void* d_ws, size_t ws_size,
                              hipStream_t stream) {
  const float* query = (const float*)d_in[0];
  const float* key   = (const float*)d_in[1];
  const float* value = (const float*)d_in[2];
  const float* ipw   = (const float*)d_in[3];
  const float* ipb   = (const float*)d_in[4];
  const float* opw   = (const float*)d_in[5];
  const float* opb   = (const float*)d_in[6];

  // workspace layout (ushort elements)
  ushort* wib = (ushort*)d_ws;       // in_proj_weight bf16 (1536x512)
  ushort* wob = wib + 786432;        // out_proj_weight bf16 (512x512)
  ushort* qp  = wob + 262144;        // projected q (2,4096,512)
  ushort* kp  = qp  + 4194304;
  ushort* vp  = kp  + 4194304;
  ushort* ctx = vp  + 4194304;       // (2,7680,512)

  const float SC = 0.125f * 1.44269504088896340736f;  // fold scale*log2e into Q

  k_cvt_w<<<512, 256, 0, stream>>>(ipw, opw, wib);

  // QKV projection from f32 inputs directly (cvt fused into A staging)
  k_gemm<<<dim3(64, 4, 3), 256, 0, stream>>>(
      nullptr, query, key, value,
      wib, (size_t)262144, ipb, 512,
      (void*)qp, (size_t)4194304, 1, SC, 1);

  k_attn<<<480, 256, 0, stream>>>(qp, kp, vp, ctx);

  // out projection (bf16 A) -> f32 d_out
  k_gemm<<<dim3(120, 4, 1), 256, 0, stream>>>(
      ctx, nullptr, nullptr, nullptr,
      wob, (size_t)0, opb, 0,
      d_out, (size_t)0, 0, 1.0f, 0);
}

// Round 10
// 83.236 us; speedup vs baseline: 1.2772x; 1.0438x over previous
//
#include <hip/hip_runtime.h>
#include <hip/hip_bf16.h>

typedef __bf16 bf16x8 __attribute__((ext_vector_type(8)));
typedef float f32x4 __attribute__((ext_vector_type(4)));
typedef float f32x16 __attribute__((ext_vector_type(16)));

__device__ __forceinline__ ushort f2bf(float f) {
  union { float f; unsigned u; } x; x.f = f;
  unsigned r = x.u + 0x7fffu + ((x.u >> 16) & 1u);
  return (ushort)(r >> 16);
}

__device__ __forceinline__ void gld_lds16(const void* g, void* l) {
  __builtin_amdgcn_global_load_lds(
      (const __attribute__((address_space(1))) void*)g,
      (__attribute__((address_space(3))) void*)l, 16, 0, 0);
}

// ---------------- f32 -> bf16 convert (weights only) ----------------
__global__ __launch_bounds__(256) void k_cvt_w(
    const float* __restrict__ wi, const float* __restrict__ wo,
    ushort* __restrict__ dst) {
  const int NWI = 196608, NWO = 65536;   // float4 counts
  const int total = NWI + NWO;
  int i = blockIdx.x * 256 + threadIdx.x;
  int stride = gridDim.x * 256;
  for (; i < total; i += stride) {
    const float* s; int j;
    if (i < NWI) { s = wi; j = i; }
    else         { s = wo; j = i - NWI; }
    float4 val = reinterpret_cast<const float4*>(s)[j];
    ushort4 o;
    o.x = f2bf(val.x); o.y = f2bf(val.y); o.z = f2bf(val.z); o.w = f2bf(val.w);
    reinterpret_cast<ushort4*>(dst)[i] = o;
  }
}

#define GK 512
#define GN 512

// ---------------- QKV GEMM: f32 A (fused cvt), double-buffered pipeline ----
// C[z] = cvt_bf16(Az) @ W[z]^T + bias[z]; z in {0,1,2} = q,k,v.
// 128x128 tile, BK=32, 256 threads (4 waves 2x2). Per iteration: issue
// kt+1 loads (B via global_load_lds -> Bs[nxt], A f32 -> regs), compute kt
// from buf[cur], cvt+ds_write A into As[nxt], ONE barrier. A-load latency
// hides under compute (T14) instead of serializing between two barriers
// (R9's 45us regression).
__global__ __launch_bounds__(256) void k_gemm_qkv(
    const float* __restrict__ za0, const float* __restrict__ za1,
    const float* __restrict__ za2,
    const ushort* __restrict__ Btbase,
    const float* __restrict__ biasbase,
    ushort* __restrict__ Cbase, float qs)
{
  int z = blockIdx.z;
  const float* A32 = (z == 0) ? za0 : (z == 1) ? za1 : za2;
  const ushort* Bt = Btbase + (size_t)262144 * z;
  const float* bias = biasbase + 512 * z;
  float osc = (z == 0) ? qs : 1.0f;

  __shared__ ushort As[2][4096];   // 2 x 8KB
  __shared__ ushort Bs[2][4096];

  int tid = threadIdx.x;
  int wv = tid >> 6, ln = tid & 63;
  int l15 = ln & 15, lg = ln >> 4;
  int wm = wv >> 1, wn = wv & 1;
  int m0 = blockIdx.x * 128, n0 = blockIdx.y * 128;

  // A staging coords: thread t owns row t>>1, k-half (t&1)*16
  int row_s = tid >> 1, kh = (tid & 1) * 16;
  const float* aP = A32 + (size_t)(m0 + row_s) * GK + kh;
  int ldsOff = row_s * 32 + kh;

  f32x4 acc[4][4] = {};

  // prologue: stage kt=0 into buffer 0
  {
#pragma unroll
    for (int h2 = 0; h2 < 2; ++h2) {
      int c = h2 * 256 + wv * 64 + ln;
      int row = c >> 2, kc = (c & 3) * 8;
      gld_lds16(Bt + (size_t)(n0 + row) * GK + kc,
                (char*)&Bs[0][0] + (h2 * 256 + wv * 64) * 16);
    }
    float4 f0 = reinterpret_cast<const float4*>(aP)[0];
    float4 f1 = reinterpret_cast<const float4*>(aP)[1];
    float4 f2 = reinterpret_cast<const float4*>(aP)[2];
    float4 f3 = reinterpret_cast<const float4*>(aP)[3];
    uint w0, w1, w2, w3, w4, w5, w6, w7;
    asm("v_cvt_pk_bf16_f32 %0, %1, %2" : "=v"(w0) : "v"(f0.x), "v"(f0.y));
    asm("v_cvt_pk_bf16_f32 %0, %1, %2" : "=v"(w1) : "v"(f0.z), "v"(f0.w));
    asm("v_cvt_pk_bf16_f32 %0, %1, %2" : "=v"(w2) : "v"(f1.x), "v"(f1.y));
    asm("v_cvt_pk_bf16_f32 %0, %1, %2" : "=v"(w3) : "v"(f1.z), "v"(f1.w));
    asm("v_cvt_pk_bf16_f32 %0, %1, %2" : "=v"(w4) : "v"(f2.x), "v"(f2.y));
    asm("v_cvt_pk_bf16_f32 %0, %1, %2" : "=v"(w5) : "v"(f2.z), "v"(f2.w));
    asm("v_cvt_pk_bf16_f32 %0, %1, %2" : "=v"(w6) : "v"(f3.x), "v"(f3.y));
    asm("v_cvt_pk_bf16_f32 %0, %1, %2" : "=v"(w7) : "v"(f3.z), "v"(f3.w));
    uint4 p0; p0.x = w0; p0.y = w1; p0.z = w2; p0.w = w3;
    uint4 p1; p1.x = w4; p1.y = w5; p1.z = w6; p1.w = w7;
    reinterpret_cast<uint4*>(&As[0][ldsOff])[0] = p0;
    reinterpret_cast<uint4*>(&As[0][ldsOff + 8])[0] = p1;
  }
  __syncthreads();

  for (int kt = 0; kt < 16; ++kt) {
    int cur = kt & 1, nxt = cur ^ 1;
    float4 f0, f1, f2, f3;
    bool pf = (kt < 15);
    if (pf) {
      // issue next B (async DMA) and next A (regs) FIRST
#pragma unroll
      for (int h2 = 0; h2 < 2; ++h2) {
        int c = h2 * 256 + wv * 64 + ln;
        int row = c >> 2, kc = (c & 3) * 8;
        gld_lds16(Bt + (size_t)(n0 + row) * GK + (kt + 1) * 32 + kc,
                  (char*)&Bs[nxt][0] + (h2 * 256 + wv * 64) * 16);
      }
      const float* ap = aP + (kt + 1) * 32;
      f0 = reinterpret_cast<const float4*>(ap)[0];
      f1 = reinterpret_cast<const float4*>(ap)[1];
      f2 = reinterpret_cast<const float4*>(ap)[2];
      f3 = reinterpret_cast<const float4*>(ap)[3];
    }

    // compute kt from buf[cur]
    bf16x8 af[4], bf4[4];
#pragma unroll
    for (int mf = 0; mf < 4; ++mf)
      af[mf] = *reinterpret_cast<const bf16x8*>(&As[cur][(wm * 64 + mf * 16 + l15) * 32 + lg * 8]);
#pragma unroll
    for (int nf = 0; nf < 4; ++nf)
      bf4[nf] = *reinterpret_cast<const bf16x8*>(&Bs[cur][(wn * 64 + nf * 16 + l15) * 32 + lg * 8]);
#pragma unroll
    for (int mf = 0; mf < 4; ++mf)
#pragma unroll
      for (int nf = 0; nf < 4; ++nf)
        acc[mf][nf] = __builtin_amdgcn_mfma_f32_16x16x32_bf16(af[mf], bf4[nf], acc[mf][nf], 0, 0, 0);

    if (pf) {
      // cvt + write A into As[nxt] (loads had the compute phase to land)
      uint w0, w1, w2, w3, w4, w5, w6, w7;
      asm("v_cvt_pk_bf16_f32 %0, %1, %2" : "=v"(w0) : "v"(f0.x), "v"(f0.y));
      asm("v_cvt_pk_bf16_f32 %0, %1, %2" : "=v"(w1) : "v"(f0.z), "v"(f0.w));
      asm("v_cvt_pk_bf16_f32 %0, %1, %2" : "=v"(w2) : "v"(f1.x), "v"(f1.y));
      asm("v_cvt_pk_bf16_f32 %0, %1, %2" : "=v"(w3) : "v"(f1.z), "v"(f1.w));
      asm("v_cvt_pk_bf16_f32 %0, %1, %2" : "=v"(w4) : "v"(f2.x), "v"(f2.y));
      asm("v_cvt_pk_bf16_f32 %0, %1, %2" : "=v"(w5) : "v"(f2.z), "v"(f2.w));
      asm("v_cvt_pk_bf16_f32 %0, %1, %2" : "=v"(w6) : "v"(f3.x), "v"(f3.y));
      asm("v_cvt_pk_bf16_f32 %0, %1, %2" : "=v"(w7) : "v"(f3.z), "v"(f3.w));
      uint4 p0; p0.x = w0; p0.y = w1; p0.z = w2; p0.w = w3;
      uint4 p1; p1.x = w4; p1.y = w5; p1.z = w6; p1.w = w7;
      reinterpret_cast<uint4*>(&As[nxt][ldsOff])[0] = p0;
      reinterpret_cast<uint4*>(&As[nxt][ldsOff + 8])[0] = p1;
    }
    __syncthreads();
  }

#pragma unroll
  for (int mf = 0; mf < 4; ++mf)
#pragma unroll
    for (int nf = 0; nf < 4; ++nf)
#pragma unroll
      for (int r = 0; r < 4; ++r) {
        int rr = m0 + wm * 64 + mf * 16 + lg * 4 + r;
        int cc = n0 + wn * 64 + nf * 16 + l15;
        float v = (acc[mf][nf][r] + bias[cc]) * osc;
        (Cbase + (size_t)4194304 * z)[(size_t)rr * GN + cc] = f2bf(v);
      }
}

// ---------------- out-proj GEMM (bf16 A via global_load_lds, f32 out) ------
__global__ __launch_bounds__(256) void k_gemm_out(
    const ushort* __restrict__ Ab, const ushort* __restrict__ Bt,
    const float* __restrict__ bias, float* __restrict__ C)
{
  __shared__ ushort As[128 * 32];
  __shared__ ushort Bs[128 * 32];

  int tid = threadIdx.x;
  int wv = tid >> 6, ln = tid & 63;
  int l15 = ln & 15, lg = ln >> 4;
  int wm = wv >> 1, wn = wv & 1;
  int m0 = blockIdx.x * 128, n0 = blockIdx.y * 128;

  f32x4 acc[4][4] = {};

  for (int kt = 0; kt < GK / 32; ++kt) {
    __syncthreads();
#pragma unroll
    for (int h2 = 0; h2 < 2; ++h2) {
      int c = h2 * 256 + wv * 64 + ln;
      int row = c >> 2, kc = (c & 3) * 8;
      gld_lds16(Ab + (size_t)(m0 + row) * GK + kt * 32 + kc,
                (char*)As + (h2 * 256 + wv * 64) * 16);
      gld_lds16(Bt + (size_t)(n0 + row) * GK + kt * 32 + kc,
                (char*)Bs + (h2 * 256 + wv * 64) * 16);
    }
    __syncthreads();
    bf16x8 af[4], bf4[4];
#pragma unroll
    for (int mf = 0; mf < 4; ++mf)
      af[mf] = *reinterpret_cast<const bf16x8*>(&As[(wm * 64 + mf * 16 + l15) * 32 + lg * 8]);
#pragma unroll
    for (int nf = 0; nf < 4; ++nf)
      bf4[nf] = *reinterpret_cast<const bf16x8*>(&Bs[(wn * 64 + nf * 16 + l15) * 32 + lg * 8]);
#pragma unroll
    for (int mf = 0; mf < 4; ++mf)
#pragma unroll
      for (int nf = 0; nf < 4; ++nf)
        acc[mf][nf] = __builtin_amdgcn_mfma_f32_16x16x32_bf16(af[mf], bf4[nf], acc[mf][nf], 0, 0, 0);
  }

#pragma unroll
  for (int mf = 0; mf < 4; ++mf)
#pragma unroll
    for (int nf = 0; nf < 4; ++nf)
#pragma unroll
      for (int r = 0; r < 4; ++r) {
        int rr = m0 + wm * 64 + mf * 16 + lg * 4 + r;
        int cc = n0 + wn * 64 + nf * 16 + l15;
        C[(size_t)rr * GN + cc] = acc[mf][nf][r] + bias[cc];
      }
}

// ---------------- sliding-window attention v7 (2 q-tiles/wave ILP) --------
// (unchanged from R8)
__global__ __launch_bounds__(256, 2) void k_attn(
    const ushort* __restrict__ qp, const ushort* __restrict__ kp,
    const ushort* __restrict__ vp, ushort* __restrict__ ctx)
{
  const int E = 512, SEQ = 4096;
  int bid0 = blockIdx.x;
  int bid = (bid0 & 7) * 60 + (bid0 >> 3);   // XCD-chunked (480 % 8 == 0)
  int qh = bid & 1;
  int h = (bid >> 1) & 7;
  int n = (bid >> 4) % 15;
  int b = bid / 240;
  int start = n * 256;

  int tid = threadIdx.x;
  int w = tid >> 6, ln = tid & 63;
  int l31 = ln & 31, hi = ln >> 5;

  size_t base = ((size_t)(b * SEQ + start)) * E + h * 64;
  const ushort* Kw = kp + base;
  const ushort* Vw = vp + base;
  const ushort* Qw = qp + base;

  __shared__ ushort Vt[32768];  // Vt[d=64][k=512], 64KB, byte^=(d&7)<<4

  {
    int sk = (tid & 63) * 8;
    int sd = (tid >> 6) * 16;
    const ushort* src = Vw + (size_t)sk * E + sd;
    union { uint4 q[2]; ushort u[16]; } R0, R1, R2, R3, R4, R5, R6, R7;
    R0.q[0] = *(const uint4*)(src + 0 * E); R0.q[1] = *(const uint4*)(src + 0 * E + 8);
    R1.q[0] = *(const uint4*)(src + 1 * E); R1.q[1] = *(const uint4*)(src + 1 * E + 8);
    R2.q[0] = *(const uint4*)(src + 2 * E); R2.q[1] = *(const uint4*)(src + 2 * E + 8);
    R3.q[0] = *(const uint4*)(src + 3 * E); R3.q[1] = *(const uint4*)(src + 3 * E + 8);
    R4.q[0] = *(const uint4*)(src + 4 * E); R4.q[1] = *(const uint4*)(src + 4 * E + 8);
    R5.q[0] = *(const uint4*)(src + 5 * E); R5.q[1] = *(const uint4*)(src + 5 * E + 8);
    R6.q[0] = *(const uint4*)(src + 6 * E); R6.q[1] = *(const uint4*)(src + 6 * E + 8);
    R7.q[0] = *(const uint4*)(src + 7 * E); R7.q[1] = *(const uint4*)(src + 7 * E + 8);
#pragma unroll
    for (int d0 = 0; d0 < 16; ++d0) {
      int d = sd + d0;
      uint4 val;
      val.x = (uint)R0.u[d0] | ((uint)R1.u[d0] << 16);
      val.y = (uint)R2.u[d0] | ((uint)R3.u[d0] << 16);
      val.z = (uint)R4.u[d0] | ((uint)R5.u[d0] << 16);
      val.w = (uint)R6.u[d0] | ((uint)R7.u[d0] << 16);
      int off = d * 1024 + ((sk * 2) ^ ((d & 7) << 4));
      *(uint4*)((char*)Vt + off) = val;
    }
  }
  __syncthreads();

  int q0 = qh * 256 + w * 64;

  bf16x8 qa0, qa1, qa2, qa3, qb0, qb1, qb2, qb3;
  {
    const ushort* qra = Qw + (size_t)(q0 + l31) * E + hi * 8;
    const ushort* qrb = qra + (size_t)32 * E;
    qa0 = *reinterpret_cast<const bf16x8*>(qra + 0);
    qa1 = *reinterpret_cast<const bf16x8*>(qra + 16);
    qa2 = *reinterpret_cast<const bf16x8*>(qra + 32);
    qa3 = *reinterpret_cast<const bf16x8*>(qra + 48);
    qb0 = *reinterpret_cast<const bf16x8*>(qrb + 0);
    qb1 = *reinterpret_cast<const bf16x8*>(qrb + 16);
    qb2 = *reinterpret_cast<const bf16x8*>(qrb + 32);
    qb3 = *reinterpret_cast<const bf16x8*>(qrb + 48);
  }

  f32x16 ca0 = {}, ca1 = {}, cb0_ = {}, cb1_ = {};
  float psa = 0.f, psb = 0.f;
  const char* lb = (const char*)Vt;

#pragma unroll
  for (int kb = 0; kb < 16; ++kb) {
    bf16x8 kf0, kf1, kf2, kf3;
    {
      const ushort* kr = Kw + (size_t)(kb * 32 + l31) * E + hi * 8;
      kf0 = *reinterpret_cast<const bf16x8*>(kr + 0);
      kf1 = *reinterpret_cast<const bf16x8*>(kr + 16);
      kf2 = *reinterpret_cast<const bf16x8*>(kr + 32);
      kf3 = *reinterpret_cast<const bf16x8*>(kr + 48);
    }
    bf16x8 vb00, vb01, vb10, vb11;
    {
      int row = l31, rowh = 32 + l31;
      int cb0 = kb * 64 + hi * 16;
      int cb1 = cb0 + 32;
      int xr0 = (row & 7) << 4;
      vb00 = *reinterpret_cast<const bf16x8*>(lb + row * 1024 + (cb0 ^ xr0));
      vb01 = *reinterpret_cast<const bf16x8*>(lb + rowh * 1024 + (cb0 ^ xr0));
      vb10 = *reinterpret_cast<const bf16x8*>(lb + row * 1024 + (cb1 ^ xr0));
      vb11 = *reinterpret_cast<const bf16x8*>(lb + rowh * 1024 + (cb1 ^ xr0));
    }

    f32x16 s1 = {}, s2 = {};
    __builtin_amdgcn_s_setprio(1);
    s1 = __builtin_amdgcn_mfma_f32_32x32x16_bf16(kf0, qa0, s1, 0, 0, 0);
    s2 = __builtin_amdgcn_mfma_f32_32x32x16_bf16(kf0, qb0, s2, 0, 0, 0);
    s1 = __builtin_amdgcn_mfma_f32_32x32x16_bf16(kf1, qa1, s1, 0, 0, 0);
    s2 = __builtin_amdgcn_mfma_f32_32x32x16_bf16(kf1, qb1, s2, 0, 0, 0);
    s1 = __builtin_amdgcn_mfma_f32_32x32x16_bf16(kf2, qa2, s1, 0, 0, 0);
    s2 = __builtin_amdgcn_mfma_f32_32x32x16_bf16(kf2, qb2, s2, 0, 0, 0);
    s1 = __builtin_amdgcn_mfma_f32_32x32x16_bf16(kf3, qa3, s1, 0, 0, 0);
    s2 = __builtin_amdgcn_mfma_f32_32x32x16_bf16(kf3, qb3, s2, 0, 0, 0);
    __builtin_amdgcn_s_setprio(0);

#pragma unroll
    for (int r = 0; r < 16; ++r) s1[r] = __builtin_amdgcn_exp2f(s1[r]);
#pragma unroll
    for (int r = 0; r < 16; ++r) s2[r] = __builtin_amdgcn_exp2f(s2[r]);
    {
      float t0 = (s1[0] + s1[1]) + (s1[2] + s1[3]);
      float t1 = (s1[4] + s1[5]) + (s1[6] + s1[7]);
      float t2 = (s1[8] + s1[9]) + (s1[10] + s1[11]);
      float t3 = (s1[12] + s1[13]) + (s1[14] + s1[15]);
      psa += (t0 + t1) + (t2 + t3);
      float u0 = (s2[0] + s2[1]) + (s2[2] + s2[3]);
      float u1 = (s2[4] + s2[5]) + (s2[6] + s2[7]);
      float u2 = (s2[8] + s2[9]) + (s2[10] + s2[11]);
      float u3 = (s2[12] + s2[13]) + (s2[14] + s2[15]);
      psb += (u0 + u1) + (u2 + u3);
    }

    uint a0, a1, a2, a3, a4, a5, a6, a7;
    asm("v_cvt_pk_bf16_f32 %0, %1, %2" : "=v"(a0) : "v"(s1[0]),  "v"(s1[1]));
    asm("v_cvt_pk_bf16_f32 %0, %1, %2" : "=v"(a1) : "v"(s1[2]),  "v"(s1[3]));
    asm("v_cvt_pk_bf16_f32 %0, %1, %2" : "=v"(a2) : "v"(s1[4]),  "v"(s1[5]));
    asm("v_cvt_pk_bf16_f32 %0, %1, %2" : "=v"(a3) : "v"(s1[6]),  "v"(s1[7]));
    asm("v_cvt_pk_bf16_f32 %0, %1, %2" : "=v"(a4) : "v"(s1[8]),  "v"(s1[9]));
    asm("v_cvt_pk_bf16_f32 %0, %1, %2" : "=v"(a5) : "v"(s1[10]), "v"(s1[11]));
    asm("v_cvt_pk_bf16_f32 %0, %1, %2" : "=v"(a6) : "v"(s1[12]), "v"(s1[13]));
    asm("v_cvt_pk_bf16_f32 %0, %1, %2" : "=v"(a7) : "v"(s1[14]), "v"(s1[15]));
    asm("v_permlane32_swap_b32 %0, %1" : "+v"(a0), "+v"(a2));
    asm("v_permlane32_swap_b32 %0, %1" : "+v"(a1), "+v"(a3));
    asm("v_permlane32_swap_b32 %0, %1" : "+v"(a4), "+v"(a6));
    asm("v_permlane32_swap_b32 %0, %1" : "+v"(a5), "+v"(a7));
    uint b0, b1, b2, b3, b4, b5, b6, b7;
    asm("v_cvt_pk_bf16_f32 %0, %1, %2" : "=v"(b0) : "v"(s2[0]),  "v"(s2[1]));
    asm("v_cvt_pk_bf16_f32 %0, %1, %2" : "=v"(b1) : "v"(s2[2]),  "v"(s2[3]));
    asm("v_cvt_pk_bf16_f32 %0, %1, %2" : "=v"(b2) : "v"(s2[4]),  "v"(s2[5]));
    asm("v_cvt_pk_bf16_f32 %0, %1, %2" : "=v"(b3) : "v"(s2[6]),  "v"(s2[7]));
    asm("v_cvt_pk_bf16_f32 %0, %1, %2" : "=v"(b4) : "v"(s2[8]),  "v"(s2[9]));
    asm("v_cvt_pk_bf16_f32 %0, %1, %2" : "=v"(b5) : "v"(s2[10]), "v"(s2[11]));
    asm("v_cvt_pk_bf16_f32 %0, %1, %2" : "=v"(b6) : "v"(s2[12]), "v"(s2[13]));
    asm("v_cvt_pk_bf16_f32 %0, %1, %2" : "=v"(b7) : "v"(s2[14]), "v"(s2[15]));
    asm("v_permlane32_swap_b32 %0, %1" : "+v"(b0), "+v"(b2));
    asm("v_permlane32_swap_b32 %0, %1" : "+v"(b1), "+v"(b3));
    asm("v_permlane32_swap_b32 %0, %1" : "+v"(b4), "+v"(b6));
    asm("v_permlane32_swap_b32 %0, %1" : "+v"(b5), "+v"(b7));
    union { uint u[4]; bf16x8 v; } A1, A2, B1, B2;
    A1.u[0] = a0; A1.u[1] = a1; A1.u[2] = a2; A1.u[3] = a3;
    A2.u[0] = a4; A2.u[1] = a5; A2.u[2] = a6; A2.u[3] = a7;
    B1.u[0] = b0; B1.u[1] = b1; B1.u[2] = b2; B1.u[3] = b3;
    B2.u[0] = b4; B2.u[1] = b5; B2.u[2] = b6; B2.u[3] = b7;

    __builtin_amdgcn_s_setprio(1);
    ca0  = __builtin_amdgcn_mfma_f32_32x32x16_bf16(A1.v, vb00, ca0, 0, 0, 0);
    cb0_ = __builtin_amdgcn_mfma_f32_32x32x16_bf16(B1.v, vb00, cb0_, 0, 0, 0);
    ca1  = __builtin_amdgcn_mfma_f32_32x32x16_bf16(A1.v, vb01, ca1, 0, 0, 0);
    cb1_ = __builtin_amdgcn_mfma_f32_32x32x16_bf16(B1.v, vb01, cb1_, 0, 0, 0);
    ca0  = __builtin_amdgcn_mfma_f32_32x32x16_bf16(A2.v, vb10, ca0, 0, 0, 0);
    cb0_ = __builtin_amdgcn_mfma_f32_32x32x16_bf16(B2.v, vb10, cb0_, 0, 0, 0);
    ca1  = __builtin_amdgcn_mfma_f32_32x32x16_bf16(A2.v, vb11, ca1, 0, 0, 0);
    cb1_ = __builtin_amdgcn_mfma_f32_32x32x16_bf16(B2.v, vb11, cb1_, 0, 0, 0);
    __builtin_amdgcn_s_setprio(0);
  }

  psa += __shfl_xor(psa, 32);
  psb += __shfl_xor(psb, 32);
  float ria = 1.0f / psa;
  float rib = 1.0f / psb;
  size_t orow0 = (size_t)b * 7680 + (size_t)n * 512 + q0;
#pragma unroll
  for (int r = 0; r < 16; ++r) {
    int qrel = (r & 3) + 8 * (r >> 2) + 4 * hi;
    float r1 = __shfl(ria, qrel);
    float r2 = __shfl(rib, qrel);
    ushort* dA = ctx + (orow0 + qrel) * E + h * 64 + l31;
    ushort* dB = ctx + (orow0 + 32 + qrel) * E + h * 64 + l31;
    dA[0]  = f2bf(ca0[r] * r1);
    dA[32] = f2bf(ca1[r] * r1);
    dB[0]  = f2bf(cb0_[r] * r2);
    dB[32] = f2bf(cb1_[r] * r2);
  }
}

// ---------------- launch ----------------
extern "C" void kernel_launch(void* const* d_in, const int* in_sizes, int n_in,
                              void* d_out, int out_size, void* d_ws, size_t ws_size,
                              hipStream_t stream) {
  const float* query = (const float*)d_in[0];
  const float* key   = (const float*)d_in[1];
  const float* value = (const float*)d_in[2];
  const float* ipw   = (const float*)d_in[3];
  const float* ipb   = (const float*)d_in[4];
  const float* opw   = (const float*)d_in[5];
  const float* opb   = (const float*)d_in[6];

  // workspace layout (ushort elements)
  ushort* wib = (ushort*)d_ws;       // in_proj_weight bf16 (1536x512)
  ushort* wob = wib + 786432;        // out_proj_weight bf16 (512x512)
  ushort* qp  = wob + 262144;        // projected q (2,4096,512)
  ushort* kp  = qp  + 4194304;
  ushort* vp  = kp  + 4194304;
  ushort* ctx = vp  + 4194304;       // (2,7680,512)

  const float SC = 0.125f * 1.44269504088896340736f;  // fold scale*log2e into Q

  k_cvt_w<<<512, 256, 0, stream>>>(ipw, opw, wib);

  k_gemm_qkv<<<dim3(64, 4, 3), 256, 0, stream>>>(
      query, key, value, wib, ipb, qp, SC);

  k_attn<<<480, 256, 0, stream>>>(qp, kp, vp, ctx);

  k_gemm_out<<<dim3(120, 4, 1), 256, 0, stream>>>(
      ctx, wob, opb, (float*)d_out);
}